// Round 1
// baseline (2871.066 us; speedup 1.0000x reference)
//
#include <hip/hip_runtime.h>
#include <math.h>

#define NPTS 4096
#define KD   64
#define BR   128                      // rows per block
#define BC   128                      // cols per tile
#define NSPLIT 4                      // column splits (partial LSE per split)
#define CT   (NPTS / (BC * NSPLIT))   // 8 col tiles per block
#define LDT  132                      // LDS row stride for [KD][128] tiles (pad 4)
#define NTHREADS 256
#define BLOG (-8.317766166719343f)    // -ln(4096)

struct FusedArgs {
  const float* X[4];
  const float* Y[4];
  const float* G[4];     // nullable (init/final passes use h = blog only)
  const float* YSQ[4];   // 0.5*|y_j|^2 of the column point set
  float* pm;             // [4][NSPLIT][NPTS] partial max
  float* ps;             // [4][NSPLIT][NPTS] partial sum
  float inv_eps;
};

struct MergeArgs {
  const float* pm;
  const float* ps;
  const float* XSQ[4];   // 0.5*|x_i|^2 of the row point set
  const float* fprev[4]; // nullable
  float* fout[4];
  float eps;
  float alpha;
  float beta;
};

// Stage a [128 rows][64 K] fp32 tile into LDS, transposed to [K][row] with an
// XOR swizzle on the row-group (g ^= (k>>3)&7) so that both the stride-4k
// transpose stores and the b128 compute reads are <=2-way bank conflicts.
__device__ __forceinline__ void load_tile(const float* __restrict__ src, float* dst,
                                          int base, int tid) {
#pragma unroll
  for (int it = 0; it < 8; ++it) {
    int linear = it * NTHREADS + tid;
    int r  = linear >> 4;    // 0..127
    int kq = linear & 15;    // float4 index along K
    float4 v = *(const float4*)(src + (size_t)(base + r) * KD + (kq << 2));
    int sg = (r >> 2) ^ (kq >> 1);      // (k>>3)&7 == kq>>1 for k=4kq+cc
    int co = (sg << 2) | (r & 3);
    int k4 = kq << 2;
    dst[(k4 + 0) * LDT + co] = v.x;
    dst[(k4 + 1) * LDT + co] = v.y;
    dst[(k4 + 2) * LDT + co] = v.z;
    dst[(k4 + 3) * LDT + co] = v.w;
  }
}

// One softmin pass for all 4 directions (blockIdx.z), column-split partials.
// f_i = xsq2_i - eps * LSE_j( q_j + dot(x_i,y_j)*inv_eps ),
//   q_j = BLOG + (g_j - ysq2_j)*inv_eps
__global__ __launch_bounds__(NTHREADS, 2)
void fused_softmin(FusedArgs A) {
  __shared__ __align__(16) float lds[KD * LDT * 2 + BC];
  float* XT = lds;
  float* YT = lds + KD * LDT;
  float* QS = lds + KD * LDT * 2;

  const int tid    = threadIdx.x;
  const int rowblk = blockIdx.x;
  const int split  = blockIdx.y;
  const int dir    = blockIdx.z;

  const float* __restrict__ Xp  = A.X[dir];
  const float* __restrict__ Yp  = A.Y[dir];
  const float* __restrict__ Gp  = A.G[dir];
  const float* __restrict__ ysq = A.YSQ[dir];
  const float inv_eps = A.inv_eps;

  const int tx = tid & 15;
  const int ty = tid >> 4;
  const int row0 = rowblk * BR;

  load_tile(Xp, XT, row0, tid);

  float rm[8], rs[8];
#pragma unroll
  for (int r = 0; r < 8; ++r) { rm[r] = -__builtin_inff(); rs[r] = 0.f; }

  for (int tile = 0; tile < CT; ++tile) {
    const int col0 = split * (CT * BC) + tile * BC;
    load_tile(Yp, YT, col0, tid);
    if (tid < BC) {
      int j = col0 + tid;
      float gv = Gp ? Gp[j] : 0.0f;
      QS[tid] = BLOG + (gv - ysq[j]) * inv_eps;
    }
    __syncthreads();

    float acc[8][8];
#pragma unroll
    for (int r = 0; r < 8; ++r)
#pragma unroll
      for (int c = 0; c < 8; ++c) acc[r][c] = 0.f;

#pragma unroll 16
    for (int k = 0; k < KD; ++k) {
      int t3 = (k >> 3) & 7;
      int xa = (ty ^ t3) << 2;
      int xb = (tx ^ t3) << 2;
      const float4 a0 = *(const float4*)(XT + k * LDT + xa);
      const float4 a1 = *(const float4*)(XT + k * LDT + 64 + xa);
      const float4 b0 = *(const float4*)(YT + k * LDT + xb);
      const float4 b1 = *(const float4*)(YT + k * LDT + 64 + xb);
      const float av[8] = {a0.x, a0.y, a0.z, a0.w, a1.x, a1.y, a1.z, a1.w};
      const float bv[8] = {b0.x, b0.y, b0.z, b0.w, b1.x, b1.y, b1.z, b1.w};
#pragma unroll
      for (int r = 0; r < 8; ++r)
#pragma unroll
        for (int c = 0; c < 8; ++c)
          acc[r][c] = fmaf(av[r], bv[c], acc[r][c]);
    }

    float qv[8];
#pragma unroll
    for (int c = 0; c < 8; ++c) {
      int lc = (c < 4) ? (tx * 4 + c) : (64 + tx * 4 + (c - 4));
      qv[c] = QS[lc];
    }
#pragma unroll
    for (int r = 0; r < 8; ++r) {
      float tv[8];
      float tmax = -__builtin_inff();
#pragma unroll
      for (int c = 0; c < 8; ++c) {
        tv[c] = fmaf(acc[r][c], inv_eps, qv[c]);
        tmax = fmaxf(tmax, tv[c]);
      }
      float mn = fmaxf(rm[r], tmax);
      float sadd = 0.f;
#pragma unroll
      for (int c = 0; c < 8; ++c) sadd += __expf(tv[c] - mn);
      rs[r] = fmaf(rs[r], __expf(rm[r] - mn), sadd);
      rm[r] = mn;
    }
    __syncthreads();
  }

  // cross-thread (tx) merge of per-row (m,s); alias onto dead XT region
  float* MM = lds;              // [16][LDT]
  float* SS = lds + 16 * LDT;   // [16][LDT]
#pragma unroll
  for (int r = 0; r < 8; ++r) {
    int lrow = (r < 4) ? (ty * 4 + r) : (64 + ty * 4 + (r - 4));
    MM[tx * LDT + lrow] = rm[r];
    SS[tx * LDT + lrow] = rs[r];
  }
  __syncthreads();
  if (tid < BR) {
    float m = -__builtin_inff();
#pragma unroll
    for (int i = 0; i < 16; ++i) m = fmaxf(m, MM[i * LDT + tid]);
    float s = 0.f;
#pragma unroll
    for (int i = 0; i < 16; ++i) s += SS[i * LDT + tid] * __expf(MM[i * LDT + tid] - m);
    size_t gi = (size_t)(dir * NSPLIT + split) * NPTS + row0 + tid;
    A.pm[gi] = m;
    A.ps[gi] = s;
  }
}

// Combine NSPLIT partials -> f value; apply Sinkhorn blend alpha*prev + beta*v.
__global__ void merge_softmin(MergeArgs A) {
  int gid = blockIdx.x * blockDim.x + threadIdx.x;  // 0..16383
  int dir = gid >> 12;
  int row = gid & (NPTS - 1);
  float ms[NSPLIT], ss[NSPLIT];
  float m = -__builtin_inff();
#pragma unroll
  for (int sp = 0; sp < NSPLIT; ++sp) {
    ms[sp] = A.pm[(size_t)(dir * NSPLIT + sp) * NPTS + row];
    ss[sp] = A.ps[(size_t)(dir * NSPLIT + sp) * NPTS + row];
    m = fmaxf(m, ms[sp]);
  }
  float s = 0.f;
#pragma unroll
  for (int sp = 0; sp < NSPLIT; ++sp) s += ss[sp] * __expf(ms[sp] - m);
  float lse = m + logf(s);
  float v = A.XSQ[dir][row] - A.eps * lse;
  float prev = A.fprev[dir] ? A.fprev[dir][row] : 0.0f;
  A.fout[dir][row] = A.alpha * prev + A.beta * v;
}

__global__ void sqnorms(const float* __restrict__ x, const float* __restrict__ y,
                        float* xs, float* ys) {
  int gid = blockIdx.x * blockDim.x + threadIdx.x;  // 0..8191
  const float* p = (gid < NPTS) ? x : y;
  float* o = (gid < NPTS) ? xs : ys;
  int row = gid & (NPTS - 1);
  const float4* r4 = (const float4*)(p + (size_t)row * KD);
  float s = 0.f;
#pragma unroll
  for (int i = 0; i < 16; ++i) {
    float4 v = r4[i];
    s += v.x * v.x + v.y * v.y + v.z * v.z + v.w * v.w;
  }
  o[row] = 0.5f * s;
}

__global__ void final_reduce(const float* __restrict__ fba, const float* __restrict__ gab,
                             const float* __restrict__ faa, const float* __restrict__ gbb,
                             float* out) {
  __shared__ float red[256];
  int t = threadIdx.x;
  float s = 0.f;
  for (int i = t; i < NPTS; i += 256)
    s += (fba[i] - faa[i]) + (gab[i] - gbb[i]);
  red[t] = s;
  __syncthreads();
  for (int off = 128; off > 0; off >>= 1) {
    if (t < off) red[t] += red[t + off];
    __syncthreads();
  }
  if (t == 0) out[0] = red[0] * (1.0f / NPTS);
}

extern "C" void kernel_launch(void* const* d_in, const int* in_sizes, int n_in,
                              void* d_out, int out_size, void* d_ws, size_t ws_size,
                              hipStream_t stream) {
  const float* x = (const float*)d_in[0];
  const float* y = (const float*)d_in[1];
  float* out = (float*)d_out;
  float* w = (float*)d_ws;

  // ws layout (floats): total 46*NPTS = 188416 floats = 736 KB
  float* xs_x = w;                  // 0.5*|x_i|^2
  float* xs_y = w + NPTS;
  float* potA = w + 2 * NPTS;       // [4][NPTS] ping
  float* potB = w + 6 * NPTS;       // [4][NPTS] pong
  float* fn   = w + 10 * NPTS;      // [4][NPTS] final potentials
  float* pm   = w + 14 * NPTS;      // [4][NSPLIT][NPTS]
  float* ps   = w + 30 * NPTS;      // [4][NSPLIT][NPTS]

  // geomloss epsilon_schedule(p=2, diameter=20, blur=0.01, scaling=0.7)
  double eps_list[32];
  int neps = 0;
  {
    double start = 2.0 * log(20.0);
    double stop  = 2.0 * log(0.01);
    double step  = 2.0 * log(0.7);
    eps_list[neps++] = 400.0;
    int cnt = (int)ceil((stop - start) / step);  // 22
    for (int i = 0; i < cnt && neps < 30; ++i) eps_list[neps++] = exp(start + (double)i * step);
    eps_list[neps++] = 1e-4;                     // neps == 24
  }

  // dir 0: ft  (rows x, cols y, g=g_ab) ; dir 1: gt  (rows y, cols x, g=f_ba)
  // dir 2: f_aa (x,x, g=f_aa)           ; dir 3: g_bb (y,y, g=g_bb)
  const float* Xd[4]   = {x, y, x, y};
  const float* Yd[4]   = {y, x, x, y};
  const float* YSQd[4] = {xs_y, xs_x, xs_x, xs_y};
  const float* XSQd[4] = {xs_x, xs_y, xs_x, xs_y};

  float* PA[4] = {potA, potA + NPTS, potA + 2 * NPTS, potA + 3 * NPTS};
  float* PB[4] = {potB, potB + NPTS, potB + 2 * NPTS, potB + 3 * NPTS};
  float* FN[4] = {fn, fn + NPTS, fn + 2 * NPTS, fn + 3 * NPTS};

  sqnorms<<<dim3(32), dim3(256), 0, stream>>>(x, y, xs_x, xs_y);

  dim3 fgrid(NPTS / BR, NSPLIT, 4);

  auto pass = [&](double eps_d, const float* const* Gd, const float* const* fprev,
                  float* const* fout, float alpha, float beta) {
    float ef = (float)eps_d;
    FusedArgs fa;
    for (int d = 0; d < 4; ++d) {
      fa.X[d] = Xd[d]; fa.Y[d] = Yd[d];
      fa.G[d] = Gd ? Gd[d] : nullptr;
      fa.YSQ[d] = YSQd[d];
    }
    fa.pm = pm; fa.ps = ps;
    fa.inv_eps = 1.0f / ef;
    fused_softmin<<<fgrid, dim3(NTHREADS), 0, stream>>>(fa);

    MergeArgs ma;
    for (int d = 0; d < 4; ++d) {
      ma.XSQ[d] = XSQd[d];
      ma.fprev[d] = fprev ? fprev[d] : nullptr;
      ma.fout[d] = fout[d];
    }
    ma.pm = pm; ma.ps = ps; ma.eps = ef; ma.alpha = alpha; ma.beta = beta;
    merge_softmin<<<dim3(64), dim3(256), 0, stream>>>(ma);
  };

  // init potentials at eps_list[0]  (h = blog, no blend)
  pass(eps_list[0], nullptr, nullptr, PA, 0.f, 1.f);

  // symmetric Sinkhorn annealing loop with 0.5 averaging
  for (int it = 0; it < neps; ++it) {
    float** R = (it & 1) ? PB : PA;  // read (old) buffers
    float** W = (it & 1) ? PA : PB;  // write (new) buffers
    const float* Gd[4] = {R[1], R[0], R[2], R[3]};
    const float* Fp[4] = {R[0], R[1], R[2], R[3]};
    pass(eps_list[it], Gd, Fp, W, 0.5f, 0.5f);
  }
  // neps even -> converged potentials live in PA

  // final extrapolation at eps = blur^p
  {
    const float* Gd[4] = {PA[1], PA[0], PA[2], PA[3]};
    pass(eps_list[neps - 1], Gd, nullptr, FN, 0.f, 1.f);
  }

  final_reduce<<<dim3(1), dim3(256), 0, stream>>>(FN[0], FN[1], FN[2], FN[3], out);
}

// Round 2
// 907.425 us; speedup vs baseline: 3.1640x; 3.1640x over previous
//
#include <hip/hip_runtime.h>
#include <hip/hip_bf16.h>
#include <math.h>

#define NPTS 4096
#define KD   64
#define BR   128                      // rows per block
#define BC   128                      // cols per tile
#define NSPLIT 4                      // column splits (partial LSE per split)
#define CT   (NPTS / (BC * NSPLIT))   // 8 col tiles per block
#define LDB  88                       // bf16 elems per LDS row: 176 B, 16B-aligned,
                                      // conflict-free b128 fragment reads
#define NTHREADS 256
#define BLOG (-8.317766166719343f)    // -ln(4096)

typedef __bf16 bf16x8 __attribute__((ext_vector_type(8)));
typedef float  f32x16 __attribute__((ext_vector_type(16)));

struct FusedArgs {
  const float* X[4];
  const float* Y[4];
  const float* G[4];     // nullable (init/final passes use h = blog only)
  const float* YSQ[4];   // 0.5*|y_j|^2 of the column point set
  float* pm;             // [4][NSPLIT][NPTS] partial max
  float* ps;             // [4][NSPLIT][NPTS] partial sum
  float inv_eps;
};

struct MergeArgs {
  const float* pm;
  const float* ps;
  const float* XSQ[4];   // 0.5*|x_i|^2 of the row point set
  const float* fprev[4]; // nullable
  float* fout[4];
  float eps;
  float alpha;
  float beta;
};

// Stage a [128 rows][64 K] fp32 tile into LDS as bf16 [128][LDB] row-major.
// 256 threads x 8 iters; each iter: one float4 load -> one 8 B LDS store.
__device__ __forceinline__ void stage_tile(const float* __restrict__ src,
                                           __bf16* dst, int base, int tid) {
#pragma unroll
  for (int it = 0; it < 8; ++it) {
    int linear = it * NTHREADS + tid;   // 0..2047
    int r  = linear >> 4;               // 0..127
    int kq = linear & 15;               // float4 index along K
    float4 v = *(const float4*)(src + (size_t)(base + r) * KD + (kq << 2));
    union { __bf16 h[4]; uint2 u; } tmp;
    tmp.h[0] = (__bf16)v.x; tmp.h[1] = (__bf16)v.y;
    tmp.h[2] = (__bf16)v.z; tmp.h[3] = (__bf16)v.w;
    *(uint2*)(dst + r * LDB + (kq << 2)) = tmp.u;
  }
}

// One softmin pass for all 4 directions (blockIdx.z), column-split partials.
// f_i = xsq2_i - eps * LSE_j( q_j + dot(x_i,y_j)*inv_eps ),
//   q_j = BLOG + (g_j - ysq2_j)*inv_eps
// Dot products via bf16 MFMA 32x32x16; online softmax in fp32 on the C-layout.
__global__ __launch_bounds__(NTHREADS, 2)
void fused_softmin(FusedArgs A) {
  __shared__ __align__(16) __bf16 XT[BR * LDB];
  __shared__ __align__(16) __bf16 YT[BC * LDB];
  __shared__ float QS[BC];

  const int tid    = threadIdx.x;
  const int lane   = tid & 63;
  const int wave   = tid >> 6;
  const int hh     = lane >> 5;   // k-half for A/B frags; row-offset bit for C
  const int ln     = lane & 31;   // row (A) / col (B,C) within 32
  const int rowblk = blockIdx.x;
  const int split  = blockIdx.y;
  const int dir    = blockIdx.z;

  const float* __restrict__ Xp  = A.X[dir];
  const float* __restrict__ Yp  = A.Y[dir];
  const float* __restrict__ Gp  = A.G[dir];
  const float* __restrict__ ysq = A.YSQ[dir];
  const float inv_eps = A.inv_eps;
  const int row0 = rowblk * BR;

  stage_tile(Xp, XT, row0, tid);

  float m[16], s[16];
#pragma unroll
  for (int r = 0; r < 16; ++r) { m[r] = -__builtin_inff(); s[r] = 0.f; }

  const __bf16* xbase = XT + (wave * 32 + ln) * LDB + hh * 8;
  const __bf16* ybase = YT + ln * LDB + hh * 8;

  for (int tile = 0; tile < CT; ++tile) {
    const int col0 = split * (CT * BC) + tile * BC;
    stage_tile(Yp, YT, col0, tid);
    if (tid < BC) {
      int j = col0 + tid;
      float gv = Gp ? Gp[j] : 0.0f;
      QS[tid] = BLOG + (gv - ysq[j]) * inv_eps;
    }
    __syncthreads();

    f32x16 acc[4];
#pragma unroll
    for (int t = 0; t < 4; ++t)
#pragma unroll
      for (int i = 0; i < 16; ++i) acc[t][i] = 0.f;

#pragma unroll
    for (int ks = 0; ks < 4; ++ks) {
      bf16x8 af = *(const bf16x8*)(xbase + ks * 16);
#pragma unroll
      for (int t = 0; t < 4; ++t) {
        bf16x8 bfv = *(const bf16x8*)(ybase + t * 32 * LDB + ks * 16);
        acc[t] = __builtin_amdgcn_mfma_f32_32x32x16_bf16(af, bfv, acc[t], 0, 0, 0);
      }
    }

    float q[4];
#pragma unroll
    for (int t = 0; t < 4; ++t) q[t] = QS[t * 32 + ln];

#pragma unroll
    for (int r = 0; r < 16; ++r) {
      float l0 = fmaf(acc[0][r], inv_eps, q[0]);
      float l1 = fmaf(acc[1][r], inv_eps, q[1]);
      float l2 = fmaf(acc[2][r], inv_eps, q[2]);
      float l3 = fmaf(acc[3][r], inv_eps, q[3]);
      float tmax = fmaxf(fmaxf(l0, l1), fmaxf(l2, l3));
      float mn = fmaxf(m[r], tmax);
      float sadd = __expf(l0 - mn) + __expf(l1 - mn) +
                   __expf(l2 - mn) + __expf(l3 - mn);
      s[r] = fmaf(s[r], __expf(m[r] - mn), sadd);
      m[r] = mn;
    }
    __syncthreads();
  }

  // cross-lane merge: each row's 32 column-owners are the lanes sharing hh
  // (xor masks 1..16 never flip lane bit 5)
#pragma unroll
  for (int r = 0; r < 16; ++r) {
#pragma unroll
    for (int d = 1; d < 32; d <<= 1) {
      float mo = __shfl_xor(m[r], d, 64);
      float so = __shfl_xor(s[r], d, 64);
      float mn = fmaxf(m[r], mo);
      s[r] = __expf(m[r] - mn) * s[r] + __expf(mo - mn) * so;
      m[r] = mn;
    }
  }
  if (ln == 0) {
#pragma unroll
    for (int r = 0; r < 16; ++r) {
      int row = row0 + wave * 32 + (r & 3) + ((r >> 2) << 3) + (hh << 2);
      size_t gi = (size_t)(dir * NSPLIT + split) * NPTS + row;
      A.pm[gi] = m[r];
      A.ps[gi] = s[r];
    }
  }
}

// Combine NSPLIT partials -> f value; apply Sinkhorn blend alpha*prev + beta*v.
__global__ void merge_softmin(MergeArgs A) {
  int gid = blockIdx.x * blockDim.x + threadIdx.x;  // 0..16383
  int dir = gid >> 12;
  int row = gid & (NPTS - 1);
  float ms[NSPLIT], ss[NSPLIT];
  float m = -__builtin_inff();
#pragma unroll
  for (int sp = 0; sp < NSPLIT; ++sp) {
    ms[sp] = A.pm[(size_t)(dir * NSPLIT + sp) * NPTS + row];
    ss[sp] = A.ps[(size_t)(dir * NSPLIT + sp) * NPTS + row];
    m = fmaxf(m, ms[sp]);
  }
  float s = 0.f;
#pragma unroll
  for (int sp = 0; sp < NSPLIT; ++sp) s += ss[sp] * __expf(ms[sp] - m);
  float lse = m + logf(s);
  float v = A.XSQ[dir][row] - A.eps * lse;
  float prev = A.fprev[dir] ? A.fprev[dir][row] : 0.0f;
  A.fout[dir][row] = A.alpha * prev + A.beta * v;
}

__global__ void sqnorms(const float* __restrict__ x, const float* __restrict__ y,
                        float* xs, float* ys) {
  int gid = blockIdx.x * blockDim.x + threadIdx.x;  // 0..8191
  const float* p = (gid < NPTS) ? x : y;
  float* o = (gid < NPTS) ? xs : ys;
  int row = gid & (NPTS - 1);
  const float4* r4 = (const float4*)(p + (size_t)row * KD);
  float s = 0.f;
#pragma unroll
  for (int i = 0; i < 16; ++i) {
    float4 v = r4[i];
    s += v.x * v.x + v.y * v.y + v.z * v.z + v.w * v.w;
  }
  o[row] = 0.5f * s;
}

__global__ void final_reduce(const float* __restrict__ fba, const float* __restrict__ gab,
                             const float* __restrict__ faa, const float* __restrict__ gbb,
                             float* out) {
  __shared__ float red[256];
  int t = threadIdx.x;
  float s = 0.f;
  for (int i = t; i < NPTS; i += 256)
    s += (fba[i] - faa[i]) + (gab[i] - gbb[i]);
  red[t] = s;
  __syncthreads();
  for (int off = 128; off > 0; off >>= 1) {
    if (t < off) red[t] += red[t + off];
    __syncthreads();
  }
  if (t == 0) out[0] = red[0] * (1.0f / NPTS);
}

extern "C" void kernel_launch(void* const* d_in, const int* in_sizes, int n_in,
                              void* d_out, int out_size, void* d_ws, size_t ws_size,
                              hipStream_t stream) {
  const float* x = (const float*)d_in[0];
  const float* y = (const float*)d_in[1];
  float* out = (float*)d_out;
  float* w = (float*)d_ws;

  // ws layout (floats): total 46*NPTS = 188416 floats = 736 KB
  float* xs_x = w;                  // 0.5*|x_i|^2
  float* xs_y = w + NPTS;
  float* potA = w + 2 * NPTS;       // [4][NPTS] ping
  float* potB = w + 6 * NPTS;       // [4][NPTS] pong
  float* fn   = w + 10 * NPTS;      // [4][NPTS] final potentials
  float* pm   = w + 14 * NPTS;      // [4][NSPLIT][NPTS]
  float* ps   = w + 30 * NPTS;      // [4][NSPLIT][NPTS]

  // geomloss epsilon_schedule(p=2, diameter=20, blur=0.01, scaling=0.7)
  double eps_list[32];
  int neps = 0;
  {
    double start = 2.0 * log(20.0);
    double stop  = 2.0 * log(0.01);
    double step  = 2.0 * log(0.7);
    eps_list[neps++] = 400.0;
    int cnt = (int)ceil((stop - start) / step);  // 22
    for (int i = 0; i < cnt && neps < 30; ++i) eps_list[neps++] = exp(start + (double)i * step);
    eps_list[neps++] = 1e-4;                     // neps == 24
  }

  // dir 0: ft  (rows x, cols y, g=g_ab) ; dir 1: gt  (rows y, cols x, g=f_ba)
  // dir 2: f_aa (x,x, g=f_aa)           ; dir 3: g_bb (y,y, g=g_bb)
  const float* Xd[4]   = {x, y, x, y};
  const float* Yd[4]   = {y, x, x, y};
  const float* YSQd[4] = {xs_y, xs_x, xs_x, xs_y};
  const float* XSQd[4] = {xs_x, xs_y, xs_x, xs_y};

  float* PA[4] = {potA, potA + NPTS, potA + 2 * NPTS, potA + 3 * NPTS};
  float* PB[4] = {potB, potB + NPTS, potB + 2 * NPTS, potB + 3 * NPTS};
  float* FN[4] = {fn, fn + NPTS, fn + 2 * NPTS, fn + 3 * NPTS};

  sqnorms<<<dim3(32), dim3(256), 0, stream>>>(x, y, xs_x, xs_y);

  dim3 fgrid(NPTS / BR, NSPLIT, 4);

  auto pass = [&](double eps_d, const float* const* Gd, const float* const* fprev,
                  float* const* fout, float alpha, float beta) {
    float ef = (float)eps_d;
    FusedArgs fa;
    for (int d = 0; d < 4; ++d) {
      fa.X[d] = Xd[d]; fa.Y[d] = Yd[d];
      fa.G[d] = Gd ? Gd[d] : nullptr;
      fa.YSQ[d] = YSQd[d];
    }
    fa.pm = pm; fa.ps = ps;
    fa.inv_eps = 1.0f / ef;
    fused_softmin<<<fgrid, dim3(NTHREADS), 0, stream>>>(fa);

    MergeArgs ma;
    for (int d = 0; d < 4; ++d) {
      ma.XSQ[d] = XSQd[d];
      ma.fprev[d] = fprev ? fprev[d] : nullptr;
      ma.fout[d] = fout[d];
    }
    ma.pm = pm; ma.ps = ps; ma.eps = ef; ma.alpha = alpha; ma.beta = beta;
    merge_softmin<<<dim3(64), dim3(256), 0, stream>>>(ma);
  };

  // init potentials at eps_list[0]  (h = blog, no blend)
  pass(eps_list[0], nullptr, nullptr, PA, 0.f, 1.f);

  // symmetric Sinkhorn annealing loop with 0.5 averaging
  for (int it = 0; it < neps; ++it) {
    float** R = (it & 1) ? PB : PA;  // read (old) buffers
    float** W = (it & 1) ? PA : PB;  // write (new) buffers
    const float* Gd[4] = {R[1], R[0], R[2], R[3]};
    const float* Fp[4] = {R[0], R[1], R[2], R[3]};
    pass(eps_list[it], Gd, Fp, W, 0.5f, 0.5f);
  }
  // neps even -> converged potentials live in PA

  // final extrapolation at eps = blur^p
  {
    const float* Gd[4] = {PA[1], PA[0], PA[2], PA[3]};
    pass(eps_list[neps - 1], Gd, nullptr, FN, 0.f, 1.f);
  }

  final_reduce<<<dim3(1), dim3(256), 0, stream>>>(FN[0], FN[1], FN[2], FN[3], out);
}